// Round 7
// baseline (141.353 us; speedup 1.0000x reference)
//
#include <hip/hip_runtime.h>

#define KP   15
#define HN   40
#define CIN  128
#define COUT 128
#define KDIM (KP*CIN)          // 1920
#define KP_EXT_INV (1.0f/1.2f)
#define AM   20                // phaseA points per block (grid 1000)
#define GBM  32                // gemm tile rows
#define GBK  128
#define GKI  (KDIM/GBK)        // 15 K-chunks

typedef __bf16 bf16x8 __attribute__((ext_vector_type(8)));
typedef __bf16 bf16x4 __attribute__((ext_vector_type(4)));
typedef float  f32x4  __attribute__((ext_vector_type(4)));

__device__ inline void async_copy16(const void* g, void* lds) {
    __builtin_amdgcn_global_load_lds(
        (const __attribute__((address_space(1))) unsigned int*)g,
        (__attribute__((address_space(3))) unsigned int*)lds, 16, 0, 0);
}
#define LGKM0() __asm__ __volatile__("s_waitcnt lgkmcnt(0)" ::: "memory")

// K-permutation (shared by wsA writer and Wt builder):
//   kc' = m*128 + q*32 + nt*4 + r   <->   kc = m*128 + nt*16 + q*4 + r
// Both wsA and Wt are stored in kc' order; GEMM dots over K so it is
// unchanged as long as BOTH sides use the same order.

// ---------------------------------------------------------------------------
// Kernel 1 (prep): x f32 -> xb bf16 (coalesced); W [1920][128] -> Wt[128][1920]
// in PERMUTED-K order: Wt[d][kc'] = W[perm(kc')][d].   (unchanged — verified)
// ---------------------------------------------------------------------------
__global__ __launch_bounds__(256)
void kpconv_prep(const float* __restrict__ x, const float* __restrict__ W,
                 __bf16* __restrict__ xb, __bf16* __restrict__ Wt,
                 int nx_elems, int nxB)
{
    const int b = blockIdx.x;
    const int t = threadIdx.x;

    if (b < nxB) {
        const int e0 = (b*256 + t) * 8;
        if (e0 + 8 <= nx_elems) {
            const float4 f0 = *(const float4*)(x + e0);
            const float4 f1 = *(const float4*)(x + e0 + 4);
            bf16x8 v;
            v[0]=(__bf16)f0.x; v[1]=(__bf16)f0.y; v[2]=(__bf16)f0.z; v[3]=(__bf16)f0.w;
            v[4]=(__bf16)f1.x; v[5]=(__bf16)f1.y; v[6]=(__bf16)f1.z; v[7]=(__bf16)f1.w;
            *(bf16x8*)(xb + e0) = v;
        } else {
            for (int e = e0; e < nx_elems; ++e) xb[e] = (__bf16)x[e];
        }
    } else {
        // one thread = one 8-granule of one d-row of Wt (permuted-K order).
        const int gid = (b - nxB)*256 + t;     // 0 .. 240*128-1
        const int gr  = gid >> 7;              // 0..239
        const int d   = gid & 127;
        bf16x8 v;
        #pragma unroll
        for (int j = 0; j < 8; ++j) {
            const int kcp = gr*8 + j;
            const int mm = kcp >> 7;
            const int qq = (kcp >> 5) & 3;
            const int nt = (kcp >> 2) & 7;
            const int rr = kcp & 3;
            const int kc = mm*128 + nt*16 + qq*4 + rr;
            v[j] = (__bf16)W[(size_t)kc*COUT + d];
        }
        *(bf16x8*)(Wt + (size_t)d*KDIM + gr*8) = v;
    }
}

// ---------------------------------------------------------------------------
// Kernel 2 (Phase A): unchanged from R6 — at its address-throughput floor
// (~1.35 cy per lane-address; xb 640 + wsA 240 + geom ~80 addrs/pt).
// ---------------------------------------------------------------------------
struct alignas(16) SharedA {
    __bf16 sXt[4][4][128][8];    // 32768 B  per-wave transpose staging (verified)
    float4 s_nd[4][2][HN];       //  5120 B  double-buffered geometry
    int    s_idx[4][2][HN];      //  1280 B
};                               // 39168 B

__global__ __launch_bounds__(256, 4)
void kpconv_phaseA(const float* __restrict__ q_pts,
                   const float* __restrict__ s_pts,
                   const int*   __restrict__ nb,
                   const __bf16* __restrict__ xb,
                   const float* __restrict__ kpts,
                   __bf16* __restrict__ wsA,
                   int N, int Ns)
{
    __shared__ SharedA sh;

    const int t  = threadIdx.x;
    const int wv = t >> 6;
    const int l  = t & 63;
    const int m  = l & 15;
    const int q  = l >> 4;
    const int m0 = blockIdx.x * AM;

    float kx=0.f, ky=0.f, kz=0.f;
    if (m < KP) { kx = kpts[m*3+0]; ky = kpts[m*3+1]; kz = kpts[m*3+2]; }
    const float kk  = kx*kx + ky*ky + kz*kz;
    const float kx2 = -2.f*kx, ky2 = -2.f*ky, kz2 = -2.f*kz;

    // ---- prologue: geometry + gathers for point 0 --------------------------
    {
        const int n0 = m0 + wv*5;
        if (l < HN) {
            int idx = nb[n0*HN + l];
            float dx, dy, dz;
            if (idx >= 0 && idx < Ns) {
                const float3 sp = *(const float3*)(s_pts + (size_t)idx*3);
                const float3 qp = *(const float3*)(q_pts + (size_t)n0*3);
                dx = sp.x - qp.x; dy = sp.y - qp.y; dz = sp.z - qp.z;
            } else { idx = 0; dx = dy = dz = 2.0e6f; }
            sh.s_idx[wv][0][l] = idx;
            sh.s_nd[wv][0][l]  = make_float4(dx, dy, dz, dx*dx+dy*dy+dz*dz);
        }
        LGKM0();
    }

    uint4 g[5][2];
    #pragma unroll
    for (int itx = 0; itx < 5; ++itx) {
        const int h0 = (itx < 4) ? (itx*8 + 2*q) : (32 + 2*q);
        g[itx][0] = *(const uint4*)(xb + (size_t)sh.s_idx[wv][0][h0  ]*CIN + m*8);
        g[itx][1] = *(const uint4*)(xb + (size_t)sh.s_idx[wv][0][h0+1]*CIN + m*8);
    }

    for (int pi = 0; pi < 5; ++pi) {
        const int cur = pi & 1;
        const int nxt = cur ^ 1;
        const int n   = m0 + wv*5 + pi;
        const bool hasNext = (pi < 4);

        // A) prefetch next point's geometry into REGISTERS
        int   p_idx = 0;
        float p_dx = 2.0e6f, p_dy = 2.0e6f, p_dz = 2.0e6f;
        if (hasNext && l < HN) {
            const int n1 = n + 1;
            int idx = nb[n1*HN + l];
            if (idx >= 0 && idx < Ns) {
                p_idx = idx;
                const float3 sp = *(const float3*)(s_pts + (size_t)idx*3);
                const float3 qp = *(const float3*)(q_pts + (size_t)n1*3);
                p_dx = sp.x - qp.x; p_dy = sp.y - qp.y; p_dz = sp.z - qp.z;
            }
        }

        // B) influence weights for this point (reads s_nd[cur])
        bf16x8 wfrag[2];
        #pragma unroll
        for (int ks = 0; ks < 2; ++ks) {
            #pragma unroll
            for (int j = 0; j < 8; ++j) {
                const int h = ks*32 + q*8 + j;
                float w = 0.f;
                if (m < KP && h < HN) {
                    const float4 nd = sh.s_nd[wv][cur][h];
                    const float d2 = fmaf(nd.x, kx2,
                                     fmaf(nd.y, ky2,
                                     fmaf(nd.z, kz2, nd.w + kk)));
                    const float d = __builtin_amdgcn_sqrtf(d2);
                    w = fmaxf(fmaf(d, -KP_EXT_INV, 1.0f), 0.f);
                }
                wfrag[ks][j] = (__bf16)w;
            }
        }

        f32x4 acc[8];
        #pragma unroll
        for (int nt = 0; nt < 8; ++nt) acc[nt] = (f32x4){0.f,0.f,0.f,0.f};

        // C) ks=0: transpose g[0..3] -> planes 0..3, MFMA x8
        #pragma unroll
        for (int itx = 0; itx < 4; ++itx) {
            const unsigned av[4] = {g[itx][0].x, g[itx][0].y, g[itx][0].z, g[itx][0].w};
            const unsigned bv[4] = {g[itx][1].x, g[itx][1].y, g[itx][1].z, g[itx][1].w};
            unsigned* plane = (unsigned*)&sh.sXt[wv][itx][0][0];
            #pragma unroll
            for (int j = 0; j < 8; ++j) {
                const unsigned v = __builtin_amdgcn_perm(
                    bv[j>>1], av[j>>1], (j&1) ? 0x07060302u : 0x05040100u);
                const int p = m*8 + (j ^ (m & 7));
                plane[p*4 + q] = v;
            }
        }
        LGKM0();
        #pragma unroll
        for (int nt = 0; nt < 8; ++nt) {
            const int cc = nt*16 + m;
            const int p  = (cc & ~7) | ((cc & 7) ^ ((cc >> 3) & 7));
            bf16x8 xf = *(const bf16x8*)&sh.sXt[wv][q][p][0];
            acc[nt] = __builtin_amdgcn_mfma_f32_16x16x32_bf16(
                          xf, wfrag[0], acc[nt], 0, 0, 0);
        }

        // D) ks=1: transpose g[4] -> plane 0 (consumes g fully)
        {
            const unsigned av[4] = {g[4][0].x, g[4][0].y, g[4][0].z, g[4][0].w};
            const unsigned bv[4] = {g[4][1].x, g[4][1].y, g[4][1].z, g[4][1].w};
            unsigned* plane = (unsigned*)&sh.sXt[wv][0][0][0];
            #pragma unroll
            for (int j = 0; j < 8; ++j) {
                const unsigned v = __builtin_amdgcn_perm(
                    bv[j>>1], av[j>>1], (j&1) ? 0x07060302u : 0x05040100u);
                const int p = m*8 + (j ^ (m & 7));
                plane[p*4 + q] = v;
            }
        }

        // E) stage next geometry to LDS + F) reissue gathers into g
        if (hasNext) {
            if (l < HN) {
                sh.s_idx[wv][nxt][l] = p_idx;
                sh.s_nd[wv][nxt][l]  = make_float4(p_dx, p_dy, p_dz,
                                                   p_dx*p_dx + p_dy*p_dy + p_dz*p_dz);
            }
            LGKM0();
            #pragma unroll
            for (int itx = 0; itx < 5; ++itx) {
                const int h0 = (itx < 4) ? (itx*8 + 2*q) : (32 + 2*q);
                g[itx][0] = *(const uint4*)(xb + (size_t)sh.s_idx[wv][nxt][h0  ]*CIN + m*8);
                g[itx][1] = *(const uint4*)(xb + (size_t)sh.s_idx[wv][nxt][h0+1]*CIN + m*8);
            }
        }

        // G) ks=1 MFMA (needs D's plane-0 writes)
        LGKM0();
        #pragma unroll
        for (int nt = 0; nt < 8; ++nt) {
            const int cc = nt*16 + m;
            const int p  = (cc & ~7) | ((cc & 7) ^ ((cc >> 3) & 7));
            bf16x8 xf = *(const bf16x8*)&sh.sXt[wv][q][p][0];
            acc[nt] = __builtin_amdgcn_mfma_f32_16x16x32_bf16(
                          xf, wfrag[1], acc[nt], 0, 0, 0);
        }

        // H) weighted rows -> wsA in PERMUTED-K layout: 4x 16B lane stores
        if (m < KP) {
            #pragma unroll
            for (int s = 0; s < 4; ++s) {
                bf16x8 v;
                #pragma unroll
                for (int r = 0; r < 4; ++r) {
                    v[r]   = (__bf16)acc[2*s  ][r];
                    v[4+r] = (__bf16)acc[2*s+1][r];
                }
                *(bf16x8*)(wsA + (size_t)n*KDIM + m*128 + q*32 + s*8) = v;
            }
        }
    }
}

// ---------------------------------------------------------------------------
// Kernel 3 (Phase B): 2-phase DOUBLE-BUFFERED staged GEMM (catalog T3-min).
// Per iteration: issue STAGE(buf^1, next k0) FIRST, then compute buf, then
// one __syncthreads() (drains vmcnt -> next buffer ready). Stage latency
// hides under the 16-MFMA compute phase; barrier count halves.
// LDS 80 KB -> 2 blocks/CU.
// ---------------------------------------------------------------------------
struct alignas(16) SharedB {
    __bf16 sA[2][GBM*GBK];       // 2 x  8 KB
    __bf16 sB[2][COUT*GBK];      // 2 x 32 KB
};                               // 81920 B

__global__ __launch_bounds__(256, 2)
void kpconv_gemm(const __bf16* __restrict__ wsA,
                 const __bf16* __restrict__ Wt,
                 float* __restrict__ out, int N)
{
    __shared__ SharedB sh;

    const int t  = threadIdx.x;
    const int wv = t >> 6;
    const int l  = t & 63;
    const int m  = l & 15;
    const int q  = l >> 4;
    const int m0 = blockIdx.x * GBM;
    const int rA = t >> 4;
    const int pA = t & 15;

    f32x4 acc[2][2];
    #pragma unroll
    for (int i = 0; i < 2; ++i)
        #pragma unroll
        for (int j = 0; j < 2; ++j) acc[i][j] = (f32x4){0.f,0.f,0.f,0.f};

    // stage one K-chunk into buffer `buf`
    auto stage = [&](int buf, int k0) {
        #pragma unroll
        for (int pass = 0; pass < 2; ++pass) {
            const int r  = rA + pass*16;
            const int ch = pA ^ (r & 15);
            async_copy16(wsA + (size_t)(m0 + r)*KDIM + k0 + ch*8,
                         (char*)sh.sA[buf] + pass*4096 + wv*1024 + l*16);
        }
        #pragma unroll
        for (int pass = 0; pass < 8; ++pass) {
            const int r  = rA + pass*16;
            const int ch = pA ^ (r & 15);
            async_copy16(Wt + (size_t)r*KDIM + k0 + ch*8,
                         (char*)sh.sB[buf] + pass*4096 + wv*1024 + l*16);
        }
    };

    stage(0, 0);
    __syncthreads();                       // buf0 ready (vmcnt(0) drained)

    int cur = 0;
    for (int it = 0; it < GKI; ++it) {
        if (it + 1 < GKI) stage(cur ^ 1, (it + 1)*GBK);   // overlaps compute

        const __bf16* sA = sh.sA[cur];
        const __bf16* sB = sh.sB[cur];
        #pragma unroll
        for (int ks = 0; ks < 4; ++ks) {
            bf16x8 af[2], bfr[2];
            #pragma unroll
            for (int mt = 0; mt < 2; ++mt) {
                const int row = mt*16 + m;
                const int p   = (ks*4 + q) ^ (row & 15);
                af[mt] = *(const bf16x8*)&sA[row*GBK + p*8];
            }
            #pragma unroll
            for (int j = 0; j < 2; ++j) {
                const int row = (wv*2 + j)*16 + m;
                const int p   = (ks*4 + q) ^ (row & 15);
                bfr[j] = *(const bf16x8*)&sB[row*GBK + p*8];
            }
            #pragma unroll
            for (int mt = 0; mt < 2; ++mt)
                #pragma unroll
                for (int j = 0; j < 2; ++j)
                    acc[mt][j] = __builtin_amdgcn_mfma_f32_16x16x32_bf16(
                                     af[mt], bfr[j], acc[mt][j], 0, 0, 0);
        }

        __syncthreads();                   // drains stage; next buf ready
        cur ^= 1;
    }

    #pragma unroll
    for (int mt = 0; mt < 2; ++mt)
        #pragma unroll
        for (int j = 0; j < 2; ++j)
            #pragma unroll
            for (int r = 0; r < 4; ++r)
                out[(size_t)(m0 + mt*16 + q*4 + r)*COUT
                    + (wv*2+j)*16 + m] = acc[mt][j][r];
}

// ---------------------------------------------------------------------------
// Fallback (round-1 fused kernel) if ws too small / shape mismatch
// ---------------------------------------------------------------------------
#define TM 8
#define WSTR (KP*CIN + 4)

__global__ __launch_bounds__(256, 2)
void kpconv_fused(const float* __restrict__ q_pts,
                  const float* __restrict__ s_pts,
                  const int*   __restrict__ nb,
                  const float* __restrict__ x,
                  const float* __restrict__ kpts,
                  const float* __restrict__ W,
                  float* __restrict__ out,
                  int N, int Ns)
{
    __shared__ float s_kp[KP*3];
    __shared__ float s_nd2[HN*3];
    __shared__ int   s_idx2[HN];
    __shared__ float s_w[KP][HN];
    __shared__ float s_wt[TM*WSTR];

    const int t  = threadIdx.x;
    const int n0 = (int)blockIdx.x * TM;
    if (t < KP*3) s_kp[t] = kpts[t];
    const int c = t & (CIN-1);
    const int g = t >> 7;

    for (int mm = 0; mm < TM; ++mm) {
        const int n = n0 + mm;
        if (t < HN) {
            float dx = 1e6f, dy = 1e6f, dz = 1e6f;
            int idx = 0;
            if (n < N) {
                idx = nb[n*HN + t];
                if (idx >= 0 && idx < Ns) {
                    dx = s_pts[idx*3+0] - q_pts[n*3+0];
                    dy = s_pts[idx*3+1] - q_pts[n*3+1];
                    dz = s_pts[idx*3+2] - q_pts[n*3+2];
                } else idx = 0;
            }
            s_idx2[t] = idx;
            s_nd2[t*3+0] = dx; s_nd2[t*3+1] = dy; s_nd2[t*3+2] = dz;
        }
        __syncthreads();
        for (int task = t; task < KP*HN; task += 256) {
            const int k = task / HN;
            const int h = task - k*HN;
            const float dx = s_nd2[h*3+0] - s_kp[k*3+0];
            const float dy = s_nd2[h*3+1] - s_kp[k*3+1];
            const float dz = s_nd2[h*3+2] - s_kp[k*3+2];
            s_w[k][h] = fmaxf(1.0f - sqrtf(dx*dx+dy*dy+dz*dz)*KP_EXT_INV, 0.0f);
        }
        __syncthreads();
        float facc[8];
        #pragma unroll
        for (int j = 0; j < 8; ++j) facc[j] = 0.0f;
        #pragma unroll 8
        for (int h = 0; h < HN; ++h) {
            const float xv = x[s_idx2[h]*CIN + c];
            #pragma unroll
            for (int j = 0; j < 8; ++j) {
                const int k = g + 2*j;
                if (k < KP) facc[j] += s_w[k][h] * xv;
            }
        }
        #pragma unroll
        for (int j = 0; j < 8; ++j) {
            const int k = g + 2*j;
            if (k < KP) s_wt[mm*WSTR + k*CIN + c] = facc[j];
        }
        __syncthreads();
    }

    const int m3 = t >> 5;
    const int d0 = (t & 31) * 4;
    const float* wm = &s_wt[m3*WSTR];
    float ax = 0.f, ay = 0.f, az = 0.f, aw = 0.f;
    #pragma unroll 4
    for (int kc = 0; kc < KP*CIN; ++kc) {
        const float  wvv = wm[kc];
        const float4 wr = *(const float4*)&W[kc*COUT + d0];
        ax += wvv * wr.x; ay += wvv * wr.y; az += wvv * wr.z; aw += wvv * wr.w;
    }
    const int n = n0 + m3;
    if (n < N) {
        float4 o; o.x = ax; o.y = ay; o.z = az; o.w = aw;
        *(float4*)&out[n*COUT + d0] = o;
    }
}

// ---------------------------------------------------------------------------
extern "C" void kernel_launch(void* const* d_in, const int* in_sizes, int n_in,
                              void* d_out, int out_size, void* d_ws, size_t ws_size,
                              hipStream_t stream) {
    const float* q_pts = (const float*)d_in[0];
    const float* s_pts = (const float*)d_in[1];
    const int*   nb    = (const int*)  d_in[2];
    const float* x     = (const float*)d_in[3];
    const float* kpts  = (const float*)d_in[4];
    const float* W     = (const float*)d_in[5];
    float* out = (float*)d_out;

    const int N  = in_sizes[0] / 3;
    const int Ns = in_sizes[1] / 3;
    const int nx = in_sizes[3];            // Ns*CIN

    const size_t needA = (size_t)N * KDIM * sizeof(__bf16);      // wsA
    const size_t needB = (size_t)COUT * KDIM * sizeof(__bf16);   // Wt
    const size_t needX = (size_t)nx * sizeof(__bf16);            // xb

    if (ws_size >= needA + needB + needX && (N % GBM) == 0 && (N % AM) == 0
        && (nx % 8) == 0 && (KDIM % GBK) == 0) {
        __bf16* wsA = (__bf16*)d_ws;
        __bf16* wsB = (__bf16*)((char*)d_ws + needA);
        __bf16* wsX = (__bf16*)((char*)d_ws + needA + needB);

        const int nxB = (nx/8 + 255) / 256;
        const int nwB = (KDIM * COUT / 8) / 256;   // 120 blocks for Wt
        hipLaunchKernelGGL(kpconv_prep, dim3(nxB + nwB), dim3(256), 0, stream,
                           x, W, wsX, wsB, nx, nxB);
        hipLaunchKernelGGL(kpconv_phaseA, dim3(N/AM), dim3(256), 0, stream,
                           q_pts, s_pts, nb, wsX, kpts, wsA, N, Ns);
        hipLaunchKernelGGL(kpconv_gemm, dim3(N/GBM), dim3(256), 0, stream,
                           wsA, wsB, out, N);
    } else {
        const int grid = (N + TM - 1) / TM;
        hipLaunchKernelGGL(kpconv_fused, dim3(grid), dim3(256), 0, stream,
                           q_pts, s_pts, nb, x, kpts, W, out, N, Ns);
    }
}

// Round 8
// 138.466 us; speedup vs baseline: 1.0208x; 1.0208x over previous
//
#include <hip/hip_runtime.h>

#define KP   15
#define HN   40
#define CIN  128
#define COUT 128
#define KDIM (KP*CIN)          // 1920
#define KP_EXT_INV (1.0f/1.2f)
#define AM   20                // phaseA points per block (grid 1000)
#define GBM  32                // gemm tile rows
#define GBK  128

typedef __bf16 bf16x8 __attribute__((ext_vector_type(8)));
typedef __bf16 bf16x4 __attribute__((ext_vector_type(4)));
typedef float  f32x4  __attribute__((ext_vector_type(4)));

__device__ inline void async_copy16(const void* g, void* lds) {
    __builtin_amdgcn_global_load_lds(
        (const __attribute__((address_space(1))) unsigned int*)g,
        (__attribute__((address_space(3))) unsigned int*)lds, 16, 0, 0);
}
#define LGKM0() __asm__ __volatile__("s_waitcnt lgkmcnt(0)" ::: "memory")

// K-permutation (shared by wsA writer and Wt builder):
//   kc' = m*128 + q*32 + nt*4 + r   <->   kc = m*128 + nt*16 + q*4 + r
// Both wsA and Wt are stored in kc' order; GEMM dots over K so it is
// unchanged as long as BOTH sides use the same order.

// ---------------------------------------------------------------------------
// Kernel 1 (prep): x f32 -> xb bf16 (coalesced); W [1920][128] -> Wt[128][1920]
// in PERMUTED-K order: Wt[d][kc'] = W[perm(kc')][d].   (unchanged — verified)
// ---------------------------------------------------------------------------
__global__ __launch_bounds__(256)
void kpconv_prep(const float* __restrict__ x, const float* __restrict__ W,
                 __bf16* __restrict__ xb, __bf16* __restrict__ Wt,
                 int nx_elems, int nxB)
{
    const int b = blockIdx.x;
    const int t = threadIdx.x;

    if (b < nxB) {
        const int e0 = (b*256 + t) * 8;
        if (e0 + 8 <= nx_elems) {
            const float4 f0 = *(const float4*)(x + e0);
            const float4 f1 = *(const float4*)(x + e0 + 4);
            bf16x8 v;
            v[0]=(__bf16)f0.x; v[1]=(__bf16)f0.y; v[2]=(__bf16)f0.z; v[3]=(__bf16)f0.w;
            v[4]=(__bf16)f1.x; v[5]=(__bf16)f1.y; v[6]=(__bf16)f1.z; v[7]=(__bf16)f1.w;
            *(bf16x8*)(xb + e0) = v;
        } else {
            for (int e = e0; e < nx_elems; ++e) xb[e] = (__bf16)x[e];
        }
    } else {
        // one thread = one 8-granule of one d-row of Wt (permuted-K order).
        const int gid = (b - nxB)*256 + t;     // 0 .. 240*128-1
        const int gr  = gid >> 7;              // 0..239
        const int d   = gid & 127;
        bf16x8 v;
        #pragma unroll
        for (int j = 0; j < 8; ++j) {
            const int kcp = gr*8 + j;
            const int mm = kcp >> 7;
            const int qq = (kcp >> 5) & 3;
            const int nt = (kcp >> 2) & 7;
            const int rr = kcp & 3;
            const int kc = mm*128 + nt*16 + qq*4 + rr;
            v[j] = (__bf16)W[(size_t)kc*COUT + d];
        }
        *(bf16x8*)(Wt + (size_t)d*KDIM + gr*8) = v;
    }
}

// ---------------------------------------------------------------------------
// Kernel 2 (Phase A): R6-verified version + uniform q_pts loads hoisted out
// of the divergent branch (scalarizable). At its address-throughput floor
// (~1.4 cy per lane-address; xb 640 + wsA 240 + geom ~80 addrs/pt).
// ---------------------------------------------------------------------------
struct alignas(16) SharedA {
    __bf16 sXt[4][4][128][8];    // 32768 B  per-wave transpose staging (verified)
    float4 s_nd[4][2][HN];       //  5120 B  double-buffered geometry
    int    s_idx[4][2][HN];      //  1280 B
};                               // 39168 B

__global__ __launch_bounds__(256, 4)
void kpconv_phaseA(const float* __restrict__ q_pts,
                   const float* __restrict__ s_pts,
                   const int*   __restrict__ nb,
                   const __bf16* __restrict__ xb,
                   const float* __restrict__ kpts,
                   __bf16* __restrict__ wsA,
                   int N, int Ns)
{
    __shared__ SharedA sh;

    const int t  = threadIdx.x;
    const int wv = t >> 6;
    const int l  = t & 63;
    const int m  = l & 15;
    const int q  = l >> 4;
    const int m0 = blockIdx.x * AM;

    float kx=0.f, ky=0.f, kz=0.f;
    if (m < KP) { kx = kpts[m*3+0]; ky = kpts[m*3+1]; kz = kpts[m*3+2]; }
    const float kk  = kx*kx + ky*ky + kz*kz;
    const float kx2 = -2.f*kx, ky2 = -2.f*ky, kz2 = -2.f*kz;

    // ---- prologue: geometry + gathers for point 0 --------------------------
    {
        const int n0 = m0 + wv*5;
        const float3 qp = *(const float3*)(q_pts + (size_t)n0*3);   // uniform
        if (l < HN) {
            int idx = nb[n0*HN + l];
            float dx, dy, dz;
            if (idx >= 0 && idx < Ns) {
                const float3 sp = *(const float3*)(s_pts + (size_t)idx*3);
                dx = sp.x - qp.x; dy = sp.y - qp.y; dz = sp.z - qp.z;
            } else { idx = 0; dx = dy = dz = 2.0e6f; }
            sh.s_idx[wv][0][l] = idx;
            sh.s_nd[wv][0][l]  = make_float4(dx, dy, dz, dx*dx+dy*dy+dz*dz);
        }
        LGKM0();
    }

    uint4 g[5][2];
    #pragma unroll
    for (int itx = 0; itx < 5; ++itx) {
        const int h0 = (itx < 4) ? (itx*8 + 2*q) : (32 + 2*q);
        g[itx][0] = *(const uint4*)(xb + (size_t)sh.s_idx[wv][0][h0  ]*CIN + m*8);
        g[itx][1] = *(const uint4*)(xb + (size_t)sh.s_idx[wv][0][h0+1]*CIN + m*8);
    }

    for (int pi = 0; pi < 5; ++pi) {
        const int cur = pi & 1;
        const int nxt = cur ^ 1;
        const int n   = m0 + wv*5 + pi;
        const bool hasNext = (pi < 4);

        // A) prefetch next point's geometry into REGISTERS
        int   p_idx = 0;
        float p_dx = 2.0e6f, p_dy = 2.0e6f, p_dz = 2.0e6f;
        if (hasNext) {
            const int n1 = n + 1;
            const float3 qp = *(const float3*)(q_pts + (size_t)n1*3);  // uniform
            if (l < HN) {
                int idx = nb[n1*HN + l];
                if (idx >= 0 && idx < Ns) {
                    p_idx = idx;
                    const float3 sp = *(const float3*)(s_pts + (size_t)idx*3);
                    p_dx = sp.x - qp.x; p_dy = sp.y - qp.y; p_dz = sp.z - qp.z;
                }
            }
        }

        // B) influence weights for this point (reads s_nd[cur])
        bf16x8 wfrag[2];
        #pragma unroll
        for (int ks = 0; ks < 2; ++ks) {
            #pragma unroll
            for (int j = 0; j < 8; ++j) {
                const int h = ks*32 + q*8 + j;
                float w = 0.f;
                if (m < KP && h < HN) {
                    const float4 nd = sh.s_nd[wv][cur][h];
                    const float d2 = fmaf(nd.x, kx2,
                                     fmaf(nd.y, ky2,
                                     fmaf(nd.z, kz2, nd.w + kk)));
                    const float d = __builtin_amdgcn_sqrtf(d2);
                    w = fmaxf(fmaf(d, -KP_EXT_INV, 1.0f), 0.f);
                }
                wfrag[ks][j] = (__bf16)w;
            }
        }

        f32x4 acc[8];
        #pragma unroll
        for (int nt = 0; nt < 8; ++nt) acc[nt] = (f32x4){0.f,0.f,0.f,0.f};

        // C) ks=0: transpose g[0..3] -> planes 0..3, MFMA x8
        #pragma unroll
        for (int itx = 0; itx < 4; ++itx) {
            const unsigned av[4] = {g[itx][0].x, g[itx][0].y, g[itx][0].z, g[itx][0].w};
            const unsigned bv[4] = {g[itx][1].x, g[itx][1].y, g[itx][1].z, g[itx][1].w};
            unsigned* plane = (unsigned*)&sh.sXt[wv][itx][0][0];
            #pragma unroll
            for (int j = 0; j < 8; ++j) {
                const unsigned v = __builtin_amdgcn_perm(
                    bv[j>>1], av[j>>1], (j&1) ? 0x07060302u : 0x05040100u);
                const int p = m*8 + (j ^ (m & 7));
                plane[p*4 + q] = v;
            }
        }
        LGKM0();
        #pragma unroll
        for (int nt = 0; nt < 8; ++nt) {
            const int cc = nt*16 + m;
            const int p  = (cc & ~7) | ((cc & 7) ^ ((cc >> 3) & 7));
            bf16x8 xf = *(const bf16x8*)&sh.sXt[wv][q][p][0];
            acc[nt] = __builtin_amdgcn_mfma_f32_16x16x32_bf16(
                          xf, wfrag[0], acc[nt], 0, 0, 0);
        }

        // D) ks=1: transpose g[4] -> plane 0 (consumes g fully)
        {
            const unsigned av[4] = {g[4][0].x, g[4][0].y, g[4][0].z, g[4][0].w};
            const unsigned bv[4] = {g[4][1].x, g[4][1].y, g[4][1].z, g[4][1].w};
            unsigned* plane = (unsigned*)&sh.sXt[wv][0][0][0];
            #pragma unroll
            for (int j = 0; j < 8; ++j) {
                const unsigned v = __builtin_amdgcn_perm(
                    bv[j>>1], av[j>>1], (j&1) ? 0x07060302u : 0x05040100u);
                const int p = m*8 + (j ^ (m & 7));
                plane[p*4 + q] = v;
            }
        }

        // E) stage next geometry to LDS + F) reissue gathers into g
        if (hasNext) {
            if (l < HN) {
                sh.s_idx[wv][nxt][l] = p_idx;
                sh.s_nd[wv][nxt][l]  = make_float4(p_dx, p_dy, p_dz,
                                                   p_dx*p_dx + p_dy*p_dy + p_dz*p_dz);
            }
            LGKM0();
            #pragma unroll
            for (int itx = 0; itx < 5; ++itx) {
                const int h0 = (itx < 4) ? (itx*8 + 2*q) : (32 + 2*q);
                g[itx][0] = *(const uint4*)(xb + (size_t)sh.s_idx[wv][nxt][h0  ]*CIN + m*8);
                g[itx][1] = *(const uint4*)(xb + (size_t)sh.s_idx[wv][nxt][h0+1]*CIN + m*8);
            }
        }

        // G) ks=1 MFMA (needs D's plane-0 writes)
        LGKM0();
        #pragma unroll
        for (int nt = 0; nt < 8; ++nt) {
            const int cc = nt*16 + m;
            const int p  = (cc & ~7) | ((cc & 7) ^ ((cc >> 3) & 7));
            bf16x8 xf = *(const bf16x8*)&sh.sXt[wv][q][p][0];
            acc[nt] = __builtin_amdgcn_mfma_f32_16x16x32_bf16(
                          xf, wfrag[1], acc[nt], 0, 0, 0);
        }

        // H) weighted rows -> wsA in PERMUTED-K layout: 4x 16B lane stores
        if (m < KP) {
            #pragma unroll
            for (int s = 0; s < 4; ++s) {
                bf16x8 v;
                #pragma unroll
                for (int r = 0; r < 4; ++r) {
                    v[r]   = (__bf16)acc[2*s  ][r];
                    v[4+r] = (__bf16)acc[2*s+1][r];
                }
                *(bf16x8*)(wsA + (size_t)n*KDIM + m*128 + q*32 + s*8) = v;
            }
        }
    }
}

// ---------------------------------------------------------------------------
// Kernel 3 (Phase B): R6's verified staged GEMM, BM=32, BK=128, single
// buffer, 40 KB LDS -> 4 blocks/CU (measured best: cross-block overlap
// beats intra-block double-buffering at halved residency).
// ---------------------------------------------------------------------------
struct alignas(16) SharedB { __bf16 sA[GBM*GBK]; __bf16 sB[COUT*GBK]; };

__global__ __launch_bounds__(256, 4)
void kpconv_gemm(const __bf16* __restrict__ wsA,
                 const __bf16* __restrict__ Wt,
                 float* __restrict__ out, int N)
{
    __shared__ SharedB sh;

    const int t  = threadIdx.x;
    const int wv = t >> 6;
    const int l  = t & 63;
    const int m  = l & 15;
    const int q  = l >> 4;
    const int m0 = blockIdx.x * GBM;
    const int rA = t >> 4;
    const int pA = t & 15;

    f32x4 acc[2][2];
    #pragma unroll
    for (int i = 0; i < 2; ++i)
        #pragma unroll
        for (int j = 0; j < 2; ++j) acc[i][j] = (f32x4){0.f,0.f,0.f,0.f};

    for (int k0 = 0; k0 < KDIM; k0 += GBK) {
        #pragma unroll
        for (int pass = 0; pass < 2; ++pass) {
            const int r  = rA + pass*16;
            const int ch = pA ^ (r & 15);
            async_copy16(wsA + (size_t)(m0 + r)*KDIM + k0 + ch*8,
                         (char*)sh.sA + pass*4096 + wv*1024 + l*16);
        }
        #pragma unroll
        for (int pass = 0; pass < 8; ++pass) {
            const int r  = rA + pass*16;
            const int ch = pA ^ (r & 15);
            async_copy16(Wt + (size_t)r*KDIM + k0 + ch*8,
                         (char*)sh.sB + pass*4096 + wv*1024 + l*16);
        }
        __syncthreads();

        #pragma unroll
        for (int ks = 0; ks < 4; ++ks) {
            bf16x8 af[2], bfr[2];
            #pragma unroll
            for (int mt = 0; mt < 2; ++mt) {
                const int row = mt*16 + m;
                const int p   = (ks*4 + q) ^ (row & 15);
                af[mt] = *(const bf16x8*)&sh.sA[row*GBK + p*8];
            }
            #pragma unroll
            for (int j = 0; j < 2; ++j) {
                const int row = (wv*2 + j)*16 + m;
                const int p   = (ks*4 + q) ^ (row & 15);
                bfr[j] = *(const bf16x8*)&sh.sB[row*GBK + p*8];
            }
            #pragma unroll
            for (int mt = 0; mt < 2; ++mt)
                #pragma unroll
                for (int j = 0; j < 2; ++j)
                    acc[mt][j] = __builtin_amdgcn_mfma_f32_16x16x32_bf16(
                                     af[mt], bfr[j], acc[mt][j], 0, 0, 0);
        }
        __syncthreads();
    }

    #pragma unroll
    for (int mt = 0; mt < 2; ++mt)
        #pragma unroll
        for (int j = 0; j < 2; ++j)
            #pragma unroll
            for (int r = 0; r < 4; ++r)
                out[(size_t)(m0 + mt*16 + q*4 + r)*COUT
                    + (wv*2+j)*16 + m] = acc[mt][j][r];
}

// ---------------------------------------------------------------------------
// Fallback (round-1 fused kernel) if ws too small / shape mismatch
// ---------------------------------------------------------------------------
#define TM 8
#define WSTR (KP*CIN + 4)

__global__ __launch_bounds__(256, 2)
void kpconv_fused(const float* __restrict__ q_pts,
                  const float* __restrict__ s_pts,
                  const int*   __restrict__ nb,
                  const float* __restrict__ x,
                  const float* __restrict__ kpts,
                  const float* __restrict__ W,
                  float* __restrict__ out,
                  int N, int Ns)
{
    __shared__ float s_kp[KP*3];
    __shared__ float s_nd2[HN*3];
    __shared__ int   s_idx2[HN];
    __shared__ float s_w[KP][HN];
    __shared__ float s_wt[TM*WSTR];

    const int t  = threadIdx.x;
    const int n0 = (int)blockIdx.x * TM;
    if (t < KP*3) s_kp[t] = kpts[t];
    const int c = t & (CIN-1);
    const int g = t >> 7;

    for (int mm = 0; mm < TM; ++mm) {
        const int n = n0 + mm;
        if (t < HN) {
            float dx = 1e6f, dy = 1e6f, dz = 1e6f;
            int idx = 0;
            if (n < N) {
                idx = nb[n*HN + t];
                if (idx >= 0 && idx < Ns) {
                    dx = s_pts[idx*3+0] - q_pts[n*3+0];
                    dy = s_pts[idx*3+1] - q_pts[n*3+1];
                    dz = s_pts[idx*3+2] - q_pts[n*3+2];
                } else idx = 0;
            }
            s_idx2[t] = idx;
            s_nd2[t*3+0] = dx; s_nd2[t*3+1] = dy; s_nd2[t*3+2] = dz;
        }
        __syncthreads();
        for (int task = t; task < KP*HN; task += 256) {
            const int k = task / HN;
            const int h = task - k*HN;
            const float dx = s_nd2[h*3+0] - s_kp[k*3+0];
            const float dy = s_nd2[h*3+1] - s_kp[k*3+1];
            const float dz = s_nd2[h*3+2] - s_kp[k*3+2];
            s_w[k][h] = fmaxf(1.0f - sqrtf(dx*dx+dy*dy+dz*dz)*KP_EXT_INV, 0.0f);
        }
        __syncthreads();
        float facc[8];
        #pragma unroll
        for (int j = 0; j < 8; ++j) facc[j] = 0.0f;
        #pragma unroll 8
        for (int h = 0; h < HN; ++h) {
            const float xv = x[s_idx2[h]*CIN + c];
            #pragma unroll
            for (int j = 0; j < 8; ++j) {
                const int k = g + 2*j;
                if (k < KP) facc[j] += s_w[k][h] * xv;
            }
        }
        #pragma unroll
        for (int j = 0; j < 8; ++j) {
            const int k = g + 2*j;
            if (k < KP) s_wt[mm*WSTR + k*CIN + c] = facc[j];
        }
        __syncthreads();
    }

    const int m3 = t >> 5;
    const int d0 = (t & 31) * 4;
    const float* wm = &s_wt[m3*WSTR];
    float ax = 0.f, ay = 0.f, az = 0.f, aw = 0.f;
    #pragma unroll 4
    for (int kc = 0; kc < KP*CIN; ++kc) {
        const float  wvv = wm[kc];
        const float4 wr = *(const float4*)&W[kc*COUT + d0];
        ax += wvv * wr.x; ay += wvv * wr.y; az += wvv * wr.z; aw += wvv * wr.w;
    }
    const int n = n0 + m3;
    if (n < N) {
        float4 o; o.x = ax; o.y = ay; o.z = az; o.w = aw;
        *(float4*)&out[n*COUT + d0] = o;
    }
}

// ---------------------------------------------------------------------------
extern "C" void kernel_launch(void* const* d_in, const int* in_sizes, int n_in,
                              void* d_out, int out_size, void* d_ws, size_t ws_size,
                              hipStream_t stream) {
    const float* q_pts = (const float*)d_in[0];
    const float* s_pts = (const float*)d_in[1];
    const int*   nb    = (const int*)  d_in[2];
    const float* x     = (const float*)d_in[3];
    const float* kpts  = (const float*)d_in[4];
    const float* W     = (const float*)d_in[5];
    float* out = (float*)d_out;

    const int N  = in_sizes[0] / 3;
    const int Ns = in_sizes[1] / 3;
    const int nx = in_sizes[3];            // Ns*CIN

    const size_t needA = (size_t)N * KDIM * sizeof(__bf16);      // wsA
    const size_t needB = (size_t)COUT * KDIM * sizeof(__bf16);   // Wt
    const size_t needX = (size_t)nx * sizeof(__bf16);            // xb

    if (ws_size >= needA + needB + needX && (N % GBM) == 0 && (N % AM) == 0
        && (nx % 8) == 0 && (KDIM % GBK) == 0) {
        __bf16* wsA = (__bf16*)d_ws;
        __bf16* wsB = (__bf16*)((char*)d_ws + needA);
        __bf16* wsX = (__bf16*)((char*)d_ws + needA + needB);

        const int nxB = (nx/8 + 255) / 256;
        const int nwB = (KDIM * COUT / 8) / 256;   // 120 blocks for Wt
        hipLaunchKernelGGL(kpconv_prep, dim3(nxB + nwB), dim3(256), 0, stream,
                           x, W, wsX, wsB, nx, nxB);
        hipLaunchKernelGGL(kpconv_phaseA, dim3(N/AM), dim3(256), 0, stream,
                           q_pts, s_pts, nb, wsX, kpts, wsA, N, Ns);
        hipLaunchKernelGGL(kpconv_gemm, dim3(N/GBM), dim3(256), 0, stream,
                           wsA, wsB, out, N);
    } else {
        const int grid = (N + TM - 1) / TM;
        hipLaunchKernelGGL(kpconv_fused, dim3(grid), dim3(256), 0, stream,
                           q_pts, s_pts, nb, x, kpts, W, out, N, Ns);
    }
}